// Round 16
// baseline (164.071 us; speedup 1.0000x reference)
//
#include <hip/hip_runtime.h>
#include <math.h>

// N=768, T=8, H=128, F=128, NZ=64, G=64, D=320, n_next=12
// ws offsets in 4-byte units.
#define H_OFF    0         // f32 [768][128]
#define C_OFF    98304     // f32 [768][128]
#define G_OFF    196608    // f32 [768][64]
#define S0_OFF   245760    // f32 [768]
#define WTD_OFF  246528    // f32 [768][128]
#define TWA_OFF  475904    // f32 [128][128] (WaT)
// bf16 MFMA B-fragment packs (dwords): tile=(nt*KT+kt), 256 dwords/tile
#define PKD1_OFF 492800    // Wd1: NT=20 KT=10 -> 51200
#define PKD2_OFF 544000    // Wd2: NT=10 KT=10 -> 25600
#define PKD3_OFF 569600    // Wd3: NT=5  KT=5  -> 6400
#define PKIH_OFF 576000    // Wih: NT=32 KT=4  -> 32768
#define PKHH_OFF 608768    // Whh: NT=32 KT=4  -> 32768

typedef short s8v __attribute__((ext_vector_type(8)));
typedef float f4v __attribute__((ext_vector_type(4)));

__device__ __forceinline__ float sigm(float x) { return 1.0f / (1.0f + __expf(-x)); }
__device__ __forceinline__ float ftanh(float x) { return 1.0f - 2.0f / (__expf(2.0f * x) + 1.0f); }
__device__ __forceinline__ float lrelu(float u) { return u >= 0.f ? u : 0.2f * u; }

__device__ __forceinline__ unsigned bf16rn(float f) {
  unsigned u = __float_as_uint(f);
  return (u + 0x7fffu + ((u >> 16) & 1u)) >> 16;
}
__device__ __forceinline__ unsigned pack2(float a, float b) {
  return bf16rn(a) | (bf16rn(b) << 16);
}
// fragment k-order bijection (same for A and B): k(g,e) = kt*32 + (e>>2)*16 + g*4 + (e&3)
__device__ __forceinline__ int fidx(int a, int k) {
  int kt = k >> 5, kk = k & 31, half = kk >> 4, rem = kk & 15;
  return (kt * 64 + (rem >> 2) * 16 + a) * 8 + half * 4 + (rem & 3);
}

// ---------------- one-time: MFMA bf16 B-frag packs + WaT ----------------
__device__ __forceinline__ void packB(const float* __restrict__ W, int K, int KT,
                                      unsigned* __restrict__ dst, int idx) {
  int t = idx >> 8, r = idx & 255, lane = r >> 2, d = r & 3;
  int nt = t / KT, kt = t % KT;
  int n = nt * 16 + (lane & 15), g = lane >> 4;
  int e0 = 2 * d, e1 = 2 * d + 1;
  int k0 = kt * 32 + ((e0 >> 2) << 4) + g * 4 + (e0 & 3);
  int k1 = kt * 32 + ((e1 >> 2) << 4) + g * 4 + (e1 & 3);
  dst[idx] = pack2(W[(size_t)n * K + k0], W[(size_t)n * K + k1]);
}

__global__ __launch_bounds__(256) void k_tr(
    const float* __restrict__ Wih, const float* __restrict__ Whh,
    const float* __restrict__ Wd1, const float* __restrict__ Wd2,
    const float* __restrict__ Wd3, const float* __restrict__ Wa,
    float* __restrict__ ws)
{
  const int idx = blockIdx.x * 256 + threadIdx.x;
  unsigned* wsu = (unsigned*)ws;
  if (idx < 16384) { int k = idx >> 7, r = idx & 127; ws[TWA_OFF + idx] = Wa[(size_t)r * 128 + k]; }
  if (idx < 51200) packB(Wd1, 320, 10, wsu + PKD1_OFF, idx);
  if (idx < 25600) packB(Wd2, 320, 10, wsu + PKD2_OFF, idx);
  if (idx < 6400)  packB(Wd3, 160, 5,  wsu + PKD3_OFF, idx);
  if (idx < 32768) {
    packB(Wih, 128, 4, wsu + PKIH_OFF, idx);
    packB(Whh, 128, 4, wsu + PKHH_OFF, idx);
  }
}

// Z-quadrant macro shared by k_enc / k_dec: one gate quadrant (nt = wid + 8*Q),
// B half-batched (4+4), A from LDS fragments, result in named f4v.
#define ZQUAD(Q, ZN, XEBUF, HBUF)                                                 \
    f4v ZN = {0.f, 0.f, 0.f, 0.f};                                               \
    {                                                                             \
      const int nt = wid + 8 * (Q);                                               \
      s8v Bv[4];                                                                  \
      _Pragma("unroll")                                                           \
      for (int kt = 0; kt < 4; ++kt)                                              \
        Bv[kt] = *(const s8v*)(pkih + ((size_t)(nt * 4 + kt) * 64 + lane) * 4);   \
      _Pragma("unroll")                                                           \
      for (int kt = 0; kt < 4; ++kt)                                              \
        ZN = __builtin_amdgcn_mfma_f32_16x16x32_bf16(                             \
            *(const s8v*)&XEBUF[(kt * 64 + lane) * 8], Bv[kt], ZN, 0, 0, 0);      \
      _Pragma("unroll")                                                           \
      for (int kt = 0; kt < 4; ++kt)                                              \
        Bv[kt] = *(const s8v*)(pkhh + ((size_t)(nt * 4 + kt) * 64 + lane) * 4);   \
      _Pragma("unroll")                                                           \
      for (int kt = 0; kt < 4; ++kt)                                              \
        ZN = __builtin_amdgcn_mfma_f32_16x16x32_bf16(                             \
            *(const s8v*)&HBUF[(kt * 64 + lane) * 8], Bv[kt], ZN, 0, 0, 0);       \
    }                                                                             \
    __builtin_amdgcn_sched_barrier(0);

// ---------------- encoder LSTM: MFMA, 16 agents/block, grid 48 ----------------
__global__ __launch_bounds__(512) void k_enc(
    const float* __restrict__ obsv, const float* __restrict__ Wemb,
    const float* __restrict__ bemb, const float* __restrict__ bih,
    const float* __restrict__ bhh, float* __restrict__ ws)
{
  __shared__ __align__(16) unsigned short hF0[4 * 64 * 8];
  __shared__ __align__(16) unsigned short hF1[4 * 64 * 8];
  __shared__ __align__(16) unsigned short xeF[4 * 64 * 8];
  __shared__ float WembS[512], bembS[128];
  __shared__ float obS[16][32];   // [agent][step*4+d]

  const int tid = threadIdx.x;
  const int wid = tid >> 6, lane = tid & 63;
  const int n0 = blockIdx.x * 16;
  const int la = lane & 15, lg = lane >> 4;
  const int abase = lg * 4;

  const unsigned* pkih = (const unsigned*)(ws) + PKIH_OFF;
  const unsigned* pkhh = (const unsigned*)(ws) + PKHH_OFF;

  WembS[tid] = Wemb[tid];
  if (tid < 128) bembS[tid] = bemb[tid];
  {
    int a = tid >> 5, td = tid & 31;
    obS[a][td] = obsv[(size_t)(n0 + a) * 32 + td];
  }
  for (int e = tid; e < 2048; e += 512) hF0[e] = 0;

  f4v cReg = {0.f, 0.f, 0.f, 0.f};
  float bzR[4];
#pragma unroll
  for (int t = 0; t < 4; ++t) { int n = (wid + 8 * t) * 16 + la; bzR[t] = bih[n] + bhh[n]; }
  __syncthreads();

  for (int step = 0; step < 8; ++step) {
    unsigned short* hCur = (step & 1) ? hF1 : hF0;
    unsigned short* hNxt = (step & 1) ? hF0 : hF1;

    // XE: xe = obsv[:,step,:] @ Wemb^T + bemb -> xeF
    {
      int a = tid & 15, jj = tid >> 4;
      float l0 = obS[a][step * 4 + 0], l1 = obS[a][step * 4 + 1];
      float l2v = obS[a][step * 4 + 2], l3 = obS[a][step * 4 + 3];
#pragma unroll
      for (int p = 0; p < 4; ++p) {
        int j = jj + 32 * p;
        float4 w = *(const float4*)&WembS[j * 4];
        float xv = bembS[j] + l0 * w.x + l1 * w.y + l2v * w.z + l3 * w.w;
        xeF[fidx(a, j)] = (unsigned short)bf16rn(xv);
      }
    }
    __syncthreads();
    // Z + gates (h0 = 0 makes step-0 Whh term vanish naturally)
    {
      ZQUAD(0, z0, xeF, hCur)
      ZQUAD(1, z1, xeF, hCur)
      ZQUAD(2, z2, xeF, hCur)
      ZQUAD(3, z3, xeF, hCur)
      int j = wid * 16 + la;
#pragma unroll
      for (int r = 0; r < 4; ++r) {
        float ci = sigm(z1[r] + bzR[1]) * cReg[r]
                 + sigm(z0[r] + bzR[0]) * ftanh(z2[r] + bzR[2]);
        cReg[r] = ci;
        float hv = sigm(z3[r] + bzR[3]) * ftanh(ci);
        hNxt[fidx(abase + r, j)] = (unsigned short)bf16rn(hv);
        if (step == 7) {
          ws[H_OFF + (size_t)(n0 + abase + r) * 128 + j] = hv;
          ws[C_OFF + (size_t)(n0 + abase + r) * 128 + j] = ci;
        }
      }
    }
    __syncthreads();
  }
}

// ---------------- social fold (unchanged) ----------------
__global__ __launch_bounds__(128) void k_social(
    const float* __restrict__ ba, const float* __restrict__ Wf3,
    const float* __restrict__ bf3, float* __restrict__ ws)
{
  __shared__ float hsh[128];
  __shared__ float Wh[128];
  const int n = blockIdx.x, t = threadIdx.x;
  hsh[t] = ws[H_OFF + (size_t)n * 128 + t];
  __syncthreads();
  float acc = ba[t];
#pragma unroll 8
  for (int k = 0; k < 128; ++k) acc += ws[TWA_OFF + (size_t)k * 128 + t] * hsh[k];
  Wh[t] = acc;
  __syncthreads();
  if (t < 64) {
    float g = 0.f;
#pragma unroll 8
    for (int f = 0; f < 128; ++f) g += Wf3[(size_t)f * 64 + t] * Wh[f];
    ws[G_OFF + (size_t)n * 64 + t] = g;
  } else {
    int l = t - 64;
    float p = bf3[l] * Wh[l] + bf3[l + 64] * Wh[l + 64];
    for (int off = 32; off > 0; off >>= 1) p += __shfl_xor(p, off);
    if (l == 0) ws[S0_OFF + n] = p;
  }
}

// ---------------- attention (unchanged) ----------------
__global__ __launch_bounds__(64) void k_attn(
    const float* __restrict__ obsv, const float* __restrict__ Wf1,
    const float* __restrict__ bf1, const float* __restrict__ Wf2,
    const float* __restrict__ bf2, float* __restrict__ ws)
{
  __shared__ float w1[96];
  __shared__ float b1[32];
  __shared__ float w2[2048];
  __shared__ float b2[64];
  __shared__ float attn_s[64];
  __shared__ float xi[4];

  const int i = blockIdx.x;
  const int b = i >> 6;
  const int lane = threadIdx.x;
  const int jn = (b << 6) + lane;

  for (int e = lane; e < 96; e += 64) w1[e] = Wf1[e];
  if (lane < 32) b1[lane] = bf1[lane];
  for (int e = lane; e < 2048; e += 64) w2[e] = Wf2[e];
  b2[lane] = bf2[lane];
  if (lane < 4) xi[lane] = obsv[((size_t)i * 8 + 7) * 4 + lane];
  __syncthreads();

  float4 xj = *(const float4*)&obsv[((size_t)jn * 8 + 7) * 4];
  float dpx = xi[0] - xj.x, dpy = xi[1] - xj.y;
  float vix = xi[2], viy = xi[3];
  float dvx = vix - xj.z, dvy = viy - xj.w;
  float l2 = sqrtf(dpx * dpx + dpy * dpy);
  float vnorm = sqrtf(vix * vix + viy * viy);
  float cosv = (dpx * vix + dpy * viy) / (l2 * vnorm + 1e-6f);
  float dv2 = dvx * dvx + dvy * dvy;
  float ttca = -(dpx * dvx + dpy * dvy) / (dv2 + 1e-6f);
  float cax = dpx + ttca * dvx, cay = dpy + ttca * dvy;
  float dca = sqrtf(cax * cax + cay * cay);

  float e1[32];
#pragma unroll
  for (int r = 0; r < 32; ++r)
    e1[r] = fmaxf(w1[r * 3 + 0] * l2 + w1[r * 3 + 1] * cosv + w1[r * 3 + 2] * dca + b1[r], 0.f);

  const float* gp = &ws[G_OFF + (size_t)jn * 64];
  float sig = ws[S0_OFF + jn];
  for (int r = 0; r < 64; ++r) {
    float a2 = b2[r];
#pragma unroll
    for (int k4 = 0; k4 < 8; ++k4) {
      float4 w = *(const float4*)&w2[r * 32 + k4 * 4];
      a2 += w.x * e1[k4 * 4 + 0] + w.y * e1[k4 * 4 + 1] + w.z * e1[k4 * 4 + 2] + w.w * e1[k4 * 4 + 3];
    }
    a2 = fmaxf(a2, 0.f);
    sig += a2 * gp[r];
  }
  if (lane == (i & 63)) sig = -1000.f;

  float m = sig;
  for (int off = 32; off > 0; off >>= 1) m = fmaxf(m, __shfl_xor(m, off));
  float ex = __expf(sig - m);
  float ssum = ex;
  for (int off = 32; off > 0; off >>= 1) ssum += __shfl_xor(ssum, off);
  attn_s[lane] = ex / ssum;
  __syncthreads();

  const float* hbase = &ws[H_OFF + (size_t)(b << 6) * 128];
  float s0a = 0.f, s1a = 0.f;
  for (int j = 0; j < 64; ++j) {
    float aj = attn_s[j];
    s0a += aj * hbase[(size_t)j * 128 + lane];
    s1a += aj * hbase[(size_t)j * 128 + 64 + lane];
  }
  ws[WTD_OFF + (size_t)i * 128 + lane] = s0a;
  ws[WTD_OFF + (size_t)i * 128 + 64 + lane] = s1a;
}

// ---------------- decoder: MFMA, 16 agents/block, grid 48 ----------------
// Register diet: U1/U2 B-batches split 5+5 (transient 20 VGPR instead of 40);
// runtime nt loops; A from LDS; in-reg Z+gates via ZQUAD.
__global__ __launch_bounds__(512) void k_dec(
    const float* __restrict__ obsv, const float* __restrict__ noise,
    const float* __restrict__ Wemb, const float* __restrict__ bemb,
    const float* __restrict__ bd1, const float* __restrict__ bd2,
    const float* __restrict__ bd3, const float* __restrict__ bd4,
    const float* __restrict__ Wd4, const float* __restrict__ bih,
    const float* __restrict__ bhh,
    float* __restrict__ ws, float* __restrict__ out)
{
  __shared__ __align__(16) unsigned short hF0[4 * 64 * 8];
  __shared__ __align__(16) unsigned short hF1[4 * 64 * 8];
  __shared__ __align__(16) unsigned short swF[6 * 64 * 8];   // wtd | noise
  __shared__ __align__(16) unsigned short u1F[10 * 64 * 8];
  __shared__ __align__(16) unsigned short u2F[5 * 64 * 8];
  __shared__ __align__(16) unsigned short xeF[4 * 64 * 8];
  __shared__ float u3S[16 * 84];
  __shared__ float lastS[64];
  __shared__ float Wd4S[160], bd4S2[2];
  __shared__ float WembS[512], bembS[128];
  __shared__ float bd1S[320], bd2S[160], bd3S[80];

  const int tid = threadIdx.x;
  const int wid = tid >> 6, lane = tid & 63;
  const int n0 = blockIdx.x * 16;
  const int la = lane & 15, lg = lane >> 4;
  const int abase = lg * 4;

  const unsigned* pkd1 = (const unsigned*)(ws) + PKD1_OFF;
  const unsigned* pkd2 = (const unsigned*)(ws) + PKD2_OFF;
  const unsigned* pkd3 = (const unsigned*)(ws) + PKD3_OFF;
  const unsigned* pkih = (const unsigned*)(ws) + PKIH_OFF;
  const unsigned* pkhh = (const unsigned*)(ws) + PKHH_OFF;

  // ---- init LDS state ----
  {
    int a = tid & 15, jj = tid >> 4;
#pragma unroll 4
    for (int p = 0; p < 4; ++p) {
      int j = jj + 32 * p;
      hF0[fidx(a, j)] = (unsigned short)bf16rn(ws[H_OFF + (size_t)(n0 + a) * 128 + j]);
      swF[fidx(a, j)] = (unsigned short)bf16rn(ws[WTD_OFF + (size_t)(n0 + a) * 128 + j]);
    }
#pragma unroll 2
    for (int p = 0; p < 2; ++p) {
      int j = jj + 32 * p;
      swF[fidx(a, 128 + j)] = (unsigned short)bf16rn(noise[(size_t)(n0 + a) * 64 + j]);
    }
  }
  if (tid < 64) lastS[tid] = obsv[((size_t)(n0 + (tid >> 2)) * 8 + 7) * 4 + (tid & 3)];
  if (tid < 160) Wd4S[tid] = Wd4[tid];
  if (tid < 2) bd4S2[tid] = bd4[tid];
  WembS[tid] = Wemb[tid];
  if (tid < 128) bembS[tid] = bemb[tid];
  if (tid < 320) bd1S[tid] = bd1[tid];
  if (tid < 160) bd2S[tid] = bd2[tid];
  if (tid < 80) bd3S[tid] = bd3[tid];

  // ---- persistent registers ----
  f4v cReg;
  {
    int j = wid * 16 + la;
#pragma unroll
    for (int r = 0; r < 4; ++r)
      cReg[r] = ws[C_OFF + (size_t)(n0 + abase + r) * 128 + j];
  }
  float bzR[4];
#pragma unroll
  for (int t = 0; t < 4; ++t) { int n = (wid + 8 * t) * 16 + la; bzR[t] = bih[n] + bhh[n]; }
  __syncthreads();

  for (int s = 0; s < 12; ++s) {
    unsigned short* hCur = (s & 1) ? hF1 : hF0;
    unsigned short* hNxt = (s & 1) ? hF0 : hF1;

    // A fragment for the 320-k input: kt<4 -> h, else swF
#define A320(kt) (*(const s8v*)((kt) < 4 ? &hCur[((kt) * 64 + lane) * 8] : &swF[(((kt) - 4) * 64 + lane) * 8]))

    // ---- U1: [16x320], runtime nt loop, two Bv[5] batches ----
    for (int nt = wid; nt < 20; nt += 8) {
      f4v acc = {0.f, 0.f, 0.f, 0.f};
      {
        s8v Bv[5];
#pragma unroll
        for (int kt = 0; kt < 5; ++kt)
          Bv[kt] = *(const s8v*)(pkd1 + ((size_t)(nt * 10 + kt) * 64 + lane) * 4);
#pragma unroll
        for (int kt = 0; kt < 5; ++kt)
          acc = __builtin_amdgcn_mfma_f32_16x16x32_bf16(A320(kt), Bv[kt], acc, 0, 0, 0);
      }
      {
        s8v Bv[5];
#pragma unroll
        for (int kt = 0; kt < 5; ++kt)
          Bv[kt] = *(const s8v*)(pkd1 + ((size_t)(nt * 10 + 5 + kt) * 64 + lane) * 4);
#pragma unroll
        for (int kt = 0; kt < 5; ++kt)
          acc = __builtin_amdgcn_mfma_f32_16x16x32_bf16(A320(5 + kt), Bv[kt], acc, 0, 0, 0);
      }
      int n = nt * 16 + la;
      float bias = bd1S[n];
#pragma unroll
      for (int r = 0; r < 4; ++r)
        u1F[fidx(abase + r, n)] = (unsigned short)bf16rn(lrelu(acc[r] + bias));
    }
#undef A320
    __syncthreads();
    // ---- U2: [16x160], runtime nt loop, two Bv[5] batches ----
    for (int nt = wid; nt < 10; nt += 8) {
      f4v acc = {0.f, 0.f, 0.f, 0.f};
      {
        s8v Bv[5];
#pragma unroll
        for (int kt = 0; kt < 5; ++kt)
          Bv[kt] = *(const s8v*)(pkd2 + ((size_t)(nt * 10 + kt) * 64 + lane) * 4);
#pragma unroll
        for (int kt = 0; kt < 5; ++kt)
          acc = __builtin_amdgcn_mfma_f32_16x16x32_bf16(
              *(const s8v*)&u1F[(kt * 64 + lane) * 8], Bv[kt], acc, 0, 0, 0);
      }
      {
        s8v Bv[5];
#pragma unroll
        for (int kt = 0; kt < 5; ++kt)
          Bv[kt] = *(const s8v*)(pkd2 + ((size_t)(nt * 10 + 5 + kt) * 64 + lane) * 4);
#pragma unroll
        for (int kt = 0; kt < 5; ++kt)
          acc = __builtin_amdgcn_mfma_f32_16x16x32_bf16(
              *(const s8v*)&u1F[((5 + kt) * 64 + lane) * 8], Bv[kt], acc, 0, 0, 0);
      }
      int n = nt * 16 + la;
      float bias = bd2S[n];
#pragma unroll
      for (int r = 0; r < 4; ++r)
        u2F[fidx(abase + r, n)] = (unsigned short)bf16rn(lrelu(acc[r] + bias));
    }
    __syncthreads();
    // ---- U3: [16x80], A from LDS ----
    if (wid < 5) {
      s8v Bv[5];
#pragma unroll
      for (int kt = 0; kt < 5; ++kt)
        Bv[kt] = *(const s8v*)(pkd3 + ((size_t)(wid * 5 + kt) * 64 + lane) * 4);
      f4v acc = {0.f, 0.f, 0.f, 0.f};
#pragma unroll
      for (int kt = 0; kt < 5; ++kt)
        acc = __builtin_amdgcn_mfma_f32_16x16x32_bf16(
            *(const s8v*)&u2F[(kt * 64 + lane) * 8], Bv[kt], acc, 0, 0, 0);
      int n = wid * 16 + la;
      float bias = bd3S[n];
#pragma unroll
      for (int r = 0; r < 4; ++r)
        u3S[(abase + r) * 84 + n] = acc[r] + bias;
    }
    __syncthreads();
    // ---- V: 2 outputs per agent; last update; out write ----
    if (tid < 128) {
      int a = tid >> 3, r = (tid >> 2) & 1, q = tid & 3;
      float part = 0.f;
#pragma unroll
      for (int i = q * 20; i < q * 20 + 20; ++i)
        part += Wd4S[r * 80 + i] * u3S[a * 84 + i];
      part += __shfl_xor(part, 1);
      part += __shfl_xor(part, 2);
      if (q == 0) {
        float v = part + bd4S2[r];
        float p = v + lastS[a * 4 + r];
        lastS[a * 4 + r] = p;
        lastS[a * 4 + 2 + r] = v;
        out[(size_t)(n0 + a) * 48 + s * 4 + r] = p;
        out[(size_t)(n0 + a) * 48 + s * 4 + 2 + r] = v;
      }
    }
    __syncthreads();
    // ---- XE ----
    {
      int a = tid & 15, jj = tid >> 4;
      float l0 = lastS[a * 4 + 0], l1 = lastS[a * 4 + 1];
      float l2v = lastS[a * 4 + 2], l3 = lastS[a * 4 + 3];
#pragma unroll
      for (int p = 0; p < 4; ++p) {
        int j = jj + 32 * p;
        float4 w = *(const float4*)&WembS[j * 4];
        float xv = bembS[j] + l0 * w.x + l1 * w.y + l2v * w.z + l3 * w.w;
        xeF[fidx(a, j)] = (unsigned short)bf16rn(xv);
      }
    }
    __syncthreads();
    // ---- Z + gates in-register ----
    {
      ZQUAD(0, z0, xeF, hCur)
      ZQUAD(1, z1, xeF, hCur)
      ZQUAD(2, z2, xeF, hCur)
      ZQUAD(3, z3, xeF, hCur)
      int j = wid * 16 + la;
#pragma unroll
      for (int r = 0; r < 4; ++r) {
        float ci = sigm(z1[r] + bzR[1]) * cReg[r]
                 + sigm(z0[r] + bzR[0]) * ftanh(z2[r] + bzR[2]);
        cReg[r] = ci;
        float hv = sigm(z3[r] + bzR[3]) * ftanh(ci);
        hNxt[fidx(abase + r, j)] = (unsigned short)bf16rn(hv);
      }
    }
    __syncthreads();
  }
}

extern "C" void kernel_launch(void* const* d_in, const int* in_sizes, int n_in,
                              void* d_out, int out_size, void* d_ws, size_t ws_size,
                              hipStream_t stream)
{
  const float* obsv = (const float*)d_in[0];
  const float* noise = (const float*)d_in[1];
  const float* Wemb = (const float*)d_in[2];
  const float* bemb = (const float*)d_in[3];
  const float* Wih = (const float*)d_in[4];
  const float* Whh = (const float*)d_in[5];
  const float* bih = (const float*)d_in[6];
  const float* bhh = (const float*)d_in[7];
  const float* Wf1 = (const float*)d_in[8];
  const float* bf1 = (const float*)d_in[9];
  const float* Wf2 = (const float*)d_in[10];
  const float* bf2 = (const float*)d_in[11];
  const float* Wf3 = (const float*)d_in[12];
  const float* bf3 = (const float*)d_in[13];
  const float* Wa = (const float*)d_in[14];
  const float* ba = (const float*)d_in[15];
  const float* Wd1 = (const float*)d_in[16];
  const float* bd1 = (const float*)d_in[17];
  const float* Wd2 = (const float*)d_in[18];
  const float* bd2 = (const float*)d_in[19];
  const float* Wd3 = (const float*)d_in[20];
  const float* bd3 = (const float*)d_in[21];
  const float* Wd4 = (const float*)d_in[22];
  const float* bd4 = (const float*)d_in[23];
  float* ws = (float*)d_ws;
  float* out = (float*)d_out;

  k_tr<<<200, 256, 0, stream>>>(Wih, Whh, Wd1, Wd2, Wd3, Wa, ws);
  k_enc<<<48, 512, 0, stream>>>(obsv, Wemb, bemb, bih, bhh, ws);
  k_social<<<768, 128, 0, stream>>>(ba, Wf3, bf3, ws);
  k_attn<<<768, 64, 0, stream>>>(obsv, Wf1, bf1, Wf2, bf2, ws);
  k_dec<<<48, 512, 0, stream>>>(obsv, noise, Wemb, bemb, bd1, bd2, bd3, bd4, Wd4,
                                bih, bhh, ws, out);
}

// Round 17
// 160.331 us; speedup vs baseline: 1.0233x; 1.0233x over previous
//
#include <hip/hip_runtime.h>
#include <math.h>

// N=768, T=8, H=128, F=128, NZ=64, G=64, D=320, n_next=12
// ws offsets in 4-byte units.
#define H_OFF    0         // f32 [768][128]
#define C_OFF    98304     // f32 [768][128]
#define G_OFF    196608    // f32 [768][64]
#define S0_OFF   245760    // f32 [768]
#define WTD_OFF  246528    // f32 [768][128]
#define TWA_OFF  475904    // f32 [128][128] (WaT)
// bf16 MFMA B-fragment packs (dwords): tile=(nt*KT+kt), 256 dwords/tile
#define PKD1_OFF 492800    // Wd1: NT=20 KT=10 -> 51200
#define PKD2_OFF 544000    // Wd2: NT=10 KT=10 -> 25600
#define PKD3_OFF 569600    // Wd3: NT=5  KT=5  -> 6400
#define PKIH_OFF 576000    // Wih: NT=32 KT=4  -> 32768
#define PKHH_OFF 608768    // Whh: NT=32 KT=4  -> 32768

typedef short s8v __attribute__((ext_vector_type(8)));
typedef float f4v __attribute__((ext_vector_type(4)));

__device__ __forceinline__ float sigm(float x) { return 1.0f / (1.0f + __expf(-x)); }
__device__ __forceinline__ float ftanh(float x) { return 1.0f - 2.0f / (__expf(2.0f * x) + 1.0f); }
__device__ __forceinline__ float lrelu(float u) { return u >= 0.f ? u : 0.2f * u; }

__device__ __forceinline__ unsigned bf16rn(float f) {
  unsigned u = __float_as_uint(f);
  return (u + 0x7fffu + ((u >> 16) & 1u)) >> 16;
}
__device__ __forceinline__ unsigned pack2(float a, float b) {
  return bf16rn(a) | (bf16rn(b) << 16);
}
// fragment k-order bijection (same for A and B): k(g,e) = kt*32 + (e>>2)*16 + g*4 + (e&3)
__device__ __forceinline__ int fidx(int a, int k) {
  int kt = k >> 5, kk = k & 31, half = kk >> 4, rem = kk & 15;
  return (kt * 64 + (rem >> 2) * 16 + a) * 8 + half * 4 + (rem & 3);
}

// ---------------- one-time: MFMA bf16 B-frag packs + WaT ----------------
__device__ __forceinline__ void packB(const float* __restrict__ W, int K, int KT,
                                      unsigned* __restrict__ dst, int idx) {
  int t = idx >> 8, r = idx & 255, lane = r >> 2, d = r & 3;
  int nt = t / KT, kt = t % KT;
  int n = nt * 16 + (lane & 15), g = lane >> 4;
  int e0 = 2 * d, e1 = 2 * d + 1;
  int k0 = kt * 32 + ((e0 >> 2) << 4) + g * 4 + (e0 & 3);
  int k1 = kt * 32 + ((e1 >> 2) << 4) + g * 4 + (e1 & 3);
  dst[idx] = pack2(W[(size_t)n * K + k0], W[(size_t)n * K + k1]);
}

__global__ __launch_bounds__(256) void k_tr(
    const float* __restrict__ Wih, const float* __restrict__ Whh,
    const float* __restrict__ Wd1, const float* __restrict__ Wd2,
    const float* __restrict__ Wd3, const float* __restrict__ Wa,
    float* __restrict__ ws)
{
  const int idx = blockIdx.x * 256 + threadIdx.x;
  unsigned* wsu = (unsigned*)ws;
  if (idx < 16384) { int k = idx >> 7, r = idx & 127; ws[TWA_OFF + idx] = Wa[(size_t)r * 128 + k]; }
  if (idx < 51200) packB(Wd1, 320, 10, wsu + PKD1_OFF, idx);
  if (idx < 25600) packB(Wd2, 320, 10, wsu + PKD2_OFF, idx);
  if (idx < 6400)  packB(Wd3, 160, 5,  wsu + PKD3_OFF, idx);
  if (idx < 32768) {
    packB(Wih, 128, 4, wsu + PKIH_OFF, idx);
    packB(Whh, 128, 4, wsu + PKHH_OFF, idx);
  }
}

// Z-quadrant macro shared by k_enc / k_dec: one gate quadrant (nt = wid + 8*Q),
// B half-batched (4+4), A from LDS fragments, result in named f4v.
#define ZQUAD(Q, ZN, XEBUF, HBUF)                                                 \
    f4v ZN = {0.f, 0.f, 0.f, 0.f};                                               \
    {                                                                             \
      const int nt = wid + 8 * (Q);                                               \
      s8v Bv[4];                                                                  \
      _Pragma("unroll")                                                           \
      for (int kt = 0; kt < 4; ++kt)                                              \
        Bv[kt] = *(const s8v*)(pkih + ((size_t)(nt * 4 + kt) * 64 + lane) * 4);   \
      _Pragma("unroll")                                                           \
      for (int kt = 0; kt < 4; ++kt)                                              \
        ZN = __builtin_amdgcn_mfma_f32_16x16x32_bf16(                             \
            *(const s8v*)&XEBUF[(kt * 64 + lane) * 8], Bv[kt], ZN, 0, 0, 0);      \
      _Pragma("unroll")                                                           \
      for (int kt = 0; kt < 4; ++kt)                                              \
        Bv[kt] = *(const s8v*)(pkhh + ((size_t)(nt * 4 + kt) * 64 + lane) * 4);   \
      _Pragma("unroll")                                                           \
      for (int kt = 0; kt < 4; ++kt)                                              \
        ZN = __builtin_amdgcn_mfma_f32_16x16x32_bf16(                             \
            *(const s8v*)&HBUF[(kt * 64 + lane) * 8], Bv[kt], ZN, 0, 0, 0);       \
    }                                                                             \
    __builtin_amdgcn_sched_barrier(0);

// ---------------- encoder LSTM: MFMA, 16 agents/block, grid 48 ----------------
__global__ __launch_bounds__(512) void k_enc(
    const float* __restrict__ obsv, const float* __restrict__ Wemb,
    const float* __restrict__ bemb, const float* __restrict__ bih,
    const float* __restrict__ bhh, float* __restrict__ ws)
{
  __shared__ __align__(16) unsigned short hF0[4 * 64 * 8];
  __shared__ __align__(16) unsigned short hF1[4 * 64 * 8];
  __shared__ __align__(16) unsigned short xeF[4 * 64 * 8];
  __shared__ float WembS[512], bembS[128];
  __shared__ float obS[16][32];   // [agent][step*4+d]

  const int tid = threadIdx.x;
  const int wid = tid >> 6, lane = tid & 63;
  const int n0 = blockIdx.x * 16;
  const int la = lane & 15, lg = lane >> 4;
  const int abase = lg * 4;

  const unsigned* pkih = (const unsigned*)(ws) + PKIH_OFF;
  const unsigned* pkhh = (const unsigned*)(ws) + PKHH_OFF;

  WembS[tid] = Wemb[tid];
  if (tid < 128) bembS[tid] = bemb[tid];
  {
    int a = tid >> 5, td = tid & 31;
    obS[a][td] = obsv[(size_t)(n0 + a) * 32 + td];
  }
  for (int e = tid; e < 2048; e += 512) hF0[e] = 0;

  f4v cReg = {0.f, 0.f, 0.f, 0.f};
  float bzR[4];
#pragma unroll
  for (int t = 0; t < 4; ++t) { int n = (wid + 8 * t) * 16 + la; bzR[t] = bih[n] + bhh[n]; }
  __syncthreads();

  for (int step = 0; step < 8; ++step) {
    unsigned short* hCur = (step & 1) ? hF1 : hF0;
    unsigned short* hNxt = (step & 1) ? hF0 : hF1;

    // XE: xe = obsv[:,step,:] @ Wemb^T + bemb -> xeF
    {
      int a = tid & 15, jj = tid >> 4;
      float l0 = obS[a][step * 4 + 0], l1 = obS[a][step * 4 + 1];
      float l2v = obS[a][step * 4 + 2], l3 = obS[a][step * 4 + 3];
#pragma unroll
      for (int p = 0; p < 4; ++p) {
        int j = jj + 32 * p;
        float4 w = *(const float4*)&WembS[j * 4];
        float xv = bembS[j] + l0 * w.x + l1 * w.y + l2v * w.z + l3 * w.w;
        xeF[fidx(a, j)] = (unsigned short)bf16rn(xv);
      }
    }
    __syncthreads();
    // Z + gates: sequential quadrants, minimal live z-state
    {
      f4v tg;
      {
        ZQUAD(2, z2, xeF, hCur)
#pragma unroll
        for (int r = 0; r < 4; ++r) tg[r] = ftanh(z2[r] + bzR[2]);
      }
      f4v cip;
      {
        ZQUAD(0, z0, xeF, hCur)
#pragma unroll
        for (int r = 0; r < 4; ++r) cip[r] = sigm(z0[r] + bzR[0]) * tg[r];
      }
      {
        ZQUAD(1, z1, xeF, hCur)
#pragma unroll
        for (int r = 0; r < 4; ++r) cReg[r] = sigm(z1[r] + bzR[1]) * cReg[r] + cip[r];
      }
      {
        ZQUAD(3, z3, xeF, hCur)
        int j = wid * 16 + la;
#pragma unroll
        for (int r = 0; r < 4; ++r) {
          float hv = sigm(z3[r] + bzR[3]) * ftanh(cReg[r]);
          hNxt[fidx(abase + r, j)] = (unsigned short)bf16rn(hv);
          if (step == 7) {
            ws[H_OFF + (size_t)(n0 + abase + r) * 128 + j] = hv;
            ws[C_OFF + (size_t)(n0 + abase + r) * 128 + j] = cReg[r];
          }
        }
      }
    }
    __syncthreads();
  }
}

// ---------------- social fold (unchanged) ----------------
__global__ __launch_bounds__(128) void k_social(
    const float* __restrict__ ba, const float* __restrict__ Wf3,
    const float* __restrict__ bf3, float* __restrict__ ws)
{
  __shared__ float hsh[128];
  __shared__ float Wh[128];
  const int n = blockIdx.x, t = threadIdx.x;
  hsh[t] = ws[H_OFF + (size_t)n * 128 + t];
  __syncthreads();
  float acc = ba[t];
#pragma unroll 8
  for (int k = 0; k < 128; ++k) acc += ws[TWA_OFF + (size_t)k * 128 + t] * hsh[k];
  Wh[t] = acc;
  __syncthreads();
  if (t < 64) {
    float g = 0.f;
#pragma unroll 8
    for (int f = 0; f < 128; ++f) g += Wf3[(size_t)f * 64 + t] * Wh[f];
    ws[G_OFF + (size_t)n * 64 + t] = g;
  } else {
    int l = t - 64;
    float p = bf3[l] * Wh[l] + bf3[l + 64] * Wh[l + 64];
    for (int off = 32; off > 0; off >>= 1) p += __shfl_xor(p, off);
    if (l == 0) ws[S0_OFF + n] = p;
  }
}

// ---------------- attention (unchanged) ----------------
__global__ __launch_bounds__(64) void k_attn(
    const float* __restrict__ obsv, const float* __restrict__ Wf1,
    const float* __restrict__ bf1, const float* __restrict__ Wf2,
    const float* __restrict__ bf2, float* __restrict__ ws)
{
  __shared__ float w1[96];
  __shared__ float b1[32];
  __shared__ float w2[2048];
  __shared__ float b2[64];
  __shared__ float attn_s[64];
  __shared__ float xi[4];

  const int i = blockIdx.x;
  const int b = i >> 6;
  const int lane = threadIdx.x;
  const int jn = (b << 6) + lane;

  for (int e = lane; e < 96; e += 64) w1[e] = Wf1[e];
  if (lane < 32) b1[lane] = bf1[lane];
  for (int e = lane; e < 2048; e += 64) w2[e] = Wf2[e];
  b2[lane] = bf2[lane];
  if (lane < 4) xi[lane] = obsv[((size_t)i * 8 + 7) * 4 + lane];
  __syncthreads();

  float4 xj = *(const float4*)&obsv[((size_t)jn * 8 + 7) * 4];
  float dpx = xi[0] - xj.x, dpy = xi[1] - xj.y;
  float vix = xi[2], viy = xi[3];
  float dvx = vix - xj.z, dvy = viy - xj.w;
  float l2 = sqrtf(dpx * dpx + dpy * dpy);
  float vnorm = sqrtf(vix * vix + viy * viy);
  float cosv = (dpx * vix + dpy * viy) / (l2 * vnorm + 1e-6f);
  float dv2 = dvx * dvx + dvy * dvy;
  float ttca = -(dpx * dvx + dpy * dvy) / (dv2 + 1e-6f);
  float cax = dpx + ttca * dvx, cay = dpy + ttca * dvy;
  float dca = sqrtf(cax * cax + cay * cay);

  float e1[32];
#pragma unroll
  for (int r = 0; r < 32; ++r)
    e1[r] = fmaxf(w1[r * 3 + 0] * l2 + w1[r * 3 + 1] * cosv + w1[r * 3 + 2] * dca + b1[r], 0.f);

  const float* gp = &ws[G_OFF + (size_t)jn * 64];
  float sig = ws[S0_OFF + jn];
  for (int r = 0; r < 64; ++r) {
    float a2 = b2[r];
#pragma unroll
    for (int k4 = 0; k4 < 8; ++k4) {
      float4 w = *(const float4*)&w2[r * 32 + k4 * 4];
      a2 += w.x * e1[k4 * 4 + 0] + w.y * e1[k4 * 4 + 1] + w.z * e1[k4 * 4 + 2] + w.w * e1[k4 * 4 + 3];
    }
    a2 = fmaxf(a2, 0.f);
    sig += a2 * gp[r];
  }
  if (lane == (i & 63)) sig = -1000.f;

  float m = sig;
  for (int off = 32; off > 0; off >>= 1) m = fmaxf(m, __shfl_xor(m, off));
  float ex = __expf(sig - m);
  float ssum = ex;
  for (int off = 32; off > 0; off >>= 1) ssum += __shfl_xor(ssum, off);
  attn_s[lane] = ex / ssum;
  __syncthreads();

  const float* hbase = &ws[H_OFF + (size_t)(b << 6) * 128];
  float s0a = 0.f, s1a = 0.f;
  for (int j = 0; j < 64; ++j) {
    float aj = attn_s[j];
    s0a += aj * hbase[(size_t)j * 128 + lane];
    s1a += aj * hbase[(size_t)j * 128 + 64 + lane];
  }
  ws[WTD_OFF + (size_t)i * 128 + lane] = s0a;
  ws[WTD_OFF + (size_t)i * 128 + 64 + lane] = s1a;
}

// ---------------- decoder: MFMA, 16 agents/block, grid 48 ----------------
// Runtime nt loops; A from LDS; 5+5 B batches; sequential-z gates (min live state).
__global__ __launch_bounds__(512) void k_dec(
    const float* __restrict__ obsv, const float* __restrict__ noise,
    const float* __restrict__ Wemb, const float* __restrict__ bemb,
    const float* __restrict__ bd1, const float* __restrict__ bd2,
    const float* __restrict__ bd3, const float* __restrict__ bd4,
    const float* __restrict__ Wd4, const float* __restrict__ bih,
    const float* __restrict__ bhh,
    float* __restrict__ ws, float* __restrict__ out)
{
  __shared__ __align__(16) unsigned short hF0[4 * 64 * 8];
  __shared__ __align__(16) unsigned short hF1[4 * 64 * 8];
  __shared__ __align__(16) unsigned short swF[6 * 64 * 8];   // wtd | noise
  __shared__ __align__(16) unsigned short u1F[10 * 64 * 8];
  __shared__ __align__(16) unsigned short u2F[5 * 64 * 8];
  __shared__ __align__(16) unsigned short xeF[4 * 64 * 8];
  __shared__ float u3S[16 * 84];
  __shared__ float lastS[64];
  __shared__ float Wd4S[160], bd4S2[2];
  __shared__ float WembS[512], bembS[128];
  __shared__ float bd1S[320], bd2S[160], bd3S[80];

  const int tid = threadIdx.x;
  const int wid = tid >> 6, lane = tid & 63;
  const int n0 = blockIdx.x * 16;
  const int la = lane & 15, lg = lane >> 4;
  const int abase = lg * 4;

  const unsigned* pkd1 = (const unsigned*)(ws) + PKD1_OFF;
  const unsigned* pkd2 = (const unsigned*)(ws) + PKD2_OFF;
  const unsigned* pkd3 = (const unsigned*)(ws) + PKD3_OFF;
  const unsigned* pkih = (const unsigned*)(ws) + PKIH_OFF;
  const unsigned* pkhh = (const unsigned*)(ws) + PKHH_OFF;

  // ---- init LDS state ----
  {
    int a = tid & 15, jj = tid >> 4;
#pragma unroll 4
    for (int p = 0; p < 4; ++p) {
      int j = jj + 32 * p;
      hF0[fidx(a, j)] = (unsigned short)bf16rn(ws[H_OFF + (size_t)(n0 + a) * 128 + j]);
      swF[fidx(a, j)] = (unsigned short)bf16rn(ws[WTD_OFF + (size_t)(n0 + a) * 128 + j]);
    }
#pragma unroll 2
    for (int p = 0; p < 2; ++p) {
      int j = jj + 32 * p;
      swF[fidx(a, 128 + j)] = (unsigned short)bf16rn(noise[(size_t)(n0 + a) * 64 + j]);
    }
  }
  if (tid < 64) lastS[tid] = obsv[((size_t)(n0 + (tid >> 2)) * 8 + 7) * 4 + (tid & 3)];
  if (tid < 160) Wd4S[tid] = Wd4[tid];
  if (tid < 2) bd4S2[tid] = bd4[tid];
  WembS[tid] = Wemb[tid];
  if (tid < 128) bembS[tid] = bemb[tid];
  if (tid < 320) bd1S[tid] = bd1[tid];
  if (tid < 160) bd2S[tid] = bd2[tid];
  if (tid < 80) bd3S[tid] = bd3[tid];

  // ---- persistent registers ----
  f4v cReg;
  {
    int j = wid * 16 + la;
#pragma unroll
    for (int r = 0; r < 4; ++r)
      cReg[r] = ws[C_OFF + (size_t)(n0 + abase + r) * 128 + j];
  }
  float bzR[4];
#pragma unroll
  for (int t = 0; t < 4; ++t) { int n = (wid + 8 * t) * 16 + la; bzR[t] = bih[n] + bhh[n]; }
  __syncthreads();

  for (int s = 0; s < 12; ++s) {
    unsigned short* hCur = (s & 1) ? hF1 : hF0;
    unsigned short* hNxt = (s & 1) ? hF0 : hF1;

    // A fragment for the 320-k input: kt<4 -> h, else swF
#define A320(kt) (*(const s8v*)((kt) < 4 ? &hCur[((kt) * 64 + lane) * 8] : &swF[(((kt) - 4) * 64 + lane) * 8]))

    // ---- U1: [16x320], runtime nt loop, two Bv[5] batches ----
    for (int nt = wid; nt < 20; nt += 8) {
      f4v acc = {0.f, 0.f, 0.f, 0.f};
      {
        s8v Bv[5];
#pragma unroll
        for (int kt = 0; kt < 5; ++kt)
          Bv[kt] = *(const s8v*)(pkd1 + ((size_t)(nt * 10 + kt) * 64 + lane) * 4);
#pragma unroll
        for (int kt = 0; kt < 5; ++kt)
          acc = __builtin_amdgcn_mfma_f32_16x16x32_bf16(A320(kt), Bv[kt], acc, 0, 0, 0);
      }
      {
        s8v Bv[5];
#pragma unroll
        for (int kt = 0; kt < 5; ++kt)
          Bv[kt] = *(const s8v*)(pkd1 + ((size_t)(nt * 10 + 5 + kt) * 64 + lane) * 4);
#pragma unroll
        for (int kt = 0; kt < 5; ++kt)
          acc = __builtin_amdgcn_mfma_f32_16x16x32_bf16(A320(5 + kt), Bv[kt], acc, 0, 0, 0);
      }
      int n = nt * 16 + la;
      float bias = bd1S[n];
#pragma unroll
      for (int r = 0; r < 4; ++r)
        u1F[fidx(abase + r, n)] = (unsigned short)bf16rn(lrelu(acc[r] + bias));
    }
#undef A320
    __syncthreads();
    // ---- U2: [16x160], runtime nt loop, two Bv[5] batches ----
    for (int nt = wid; nt < 10; nt += 8) {
      f4v acc = {0.f, 0.f, 0.f, 0.f};
      {
        s8v Bv[5];
#pragma unroll
        for (int kt = 0; kt < 5; ++kt)
          Bv[kt] = *(const s8v*)(pkd2 + ((size_t)(nt * 10 + kt) * 64 + lane) * 4);
#pragma unroll
        for (int kt = 0; kt < 5; ++kt)
          acc = __builtin_amdgcn_mfma_f32_16x16x32_bf16(
              *(const s8v*)&u1F[(kt * 64 + lane) * 8], Bv[kt], acc, 0, 0, 0);
      }
      {
        s8v Bv[5];
#pragma unroll
        for (int kt = 0; kt < 5; ++kt)
          Bv[kt] = *(const s8v*)(pkd2 + ((size_t)(nt * 10 + 5 + kt) * 64 + lane) * 4);
#pragma unroll
        for (int kt = 0; kt < 5; ++kt)
          acc = __builtin_amdgcn_mfma_f32_16x16x32_bf16(
              *(const s8v*)&u1F[((5 + kt) * 64 + lane) * 8], Bv[kt], acc, 0, 0, 0);
      }
      int n = nt * 16 + la;
      float bias = bd2S[n];
#pragma unroll
      for (int r = 0; r < 4; ++r)
        u2F[fidx(abase + r, n)] = (unsigned short)bf16rn(lrelu(acc[r] + bias));
    }
    __syncthreads();
    // ---- U3: [16x80], A from LDS ----
    if (wid < 5) {
      s8v Bv[5];
#pragma unroll
      for (int kt = 0; kt < 5; ++kt)
        Bv[kt] = *(const s8v*)(pkd3 + ((size_t)(wid * 5 + kt) * 64 + lane) * 4);
      f4v acc = {0.f, 0.f, 0.f, 0.f};
#pragma unroll
      for (int kt = 0; kt < 5; ++kt)
        acc = __builtin_amdgcn_mfma_f32_16x16x32_bf16(
            *(const s8v*)&u2F[(kt * 64 + lane) * 8], Bv[kt], acc, 0, 0, 0);
      int n = wid * 16 + la;
      float bias = bd3S[n];
#pragma unroll
      for (int r = 0; r < 4; ++r)
        u3S[(abase + r) * 84 + n] = acc[r] + bias;
    }
    __syncthreads();
    // ---- V: 2 outputs per agent; last update; out write ----
    if (tid < 128) {
      int a = tid >> 3, r = (tid >> 2) & 1, q = tid & 3;
      float part = 0.f;
#pragma unroll
      for (int i = q * 20; i < q * 20 + 20; ++i)
        part += Wd4S[r * 80 + i] * u3S[a * 84 + i];
      part += __shfl_xor(part, 1);
      part += __shfl_xor(part, 2);
      if (q == 0) {
        float v = part + bd4S2[r];
        float p = v + lastS[a * 4 + r];
        lastS[a * 4 + r] = p;
        lastS[a * 4 + 2 + r] = v;
        out[(size_t)(n0 + a) * 48 + s * 4 + r] = p;
        out[(size_t)(n0 + a) * 48 + s * 4 + 2 + r] = v;
      }
    }
    __syncthreads();
    // ---- XE ----
    {
      int a = tid & 15, jj = tid >> 4;
      float l0 = lastS[a * 4 + 0], l1 = lastS[a * 4 + 1];
      float l2v = lastS[a * 4 + 2], l3 = lastS[a * 4 + 3];
#pragma unroll
      for (int p = 0; p < 4; ++p) {
        int j = jj + 32 * p;
        float4 w = *(const float4*)&WembS[j * 4];
        float xv = bembS[j] + l0 * w.x + l1 * w.y + l2v * w.z + l3 * w.w;
        xeF[fidx(a, j)] = (unsigned short)bf16rn(xv);
      }
    }
    __syncthreads();
    // ---- Z + gates: sequential quadrants, minimal live z-state ----
    {
      f4v tg;
      {
        ZQUAD(2, z2, xeF, hCur)
#pragma unroll
        for (int r = 0; r < 4; ++r) tg[r] = ftanh(z2[r] + bzR[2]);
      }
      f4v cip;
      {
        ZQUAD(0, z0, xeF, hCur)
#pragma unroll
        for (int r = 0; r < 4; ++r) cip[r] = sigm(z0[r] + bzR[0]) * tg[r];
      }
      {
        ZQUAD(1, z1, xeF, hCur)
#pragma unroll
        for (int r = 0; r < 4; ++r) cReg[r] = sigm(z1[r] + bzR[1]) * cReg[r] + cip[r];
      }
      {
        ZQUAD(3, z3, xeF, hCur)
        int j = wid * 16 + la;
#pragma unroll
        for (int r = 0; r < 4; ++r) {
          float hv = sigm(z3[r] + bzR[3]) * ftanh(cReg[r]);
          hNxt[fidx(abase + r, j)] = (unsigned short)bf16rn(hv);
        }
      }
    }
    __syncthreads();
  }
}

extern "C" void kernel_launch(void* const* d_in, const int* in_sizes, int n_in,
                              void* d_out, int out_size, void* d_ws, size_t ws_size,
                              hipStream_t stream)
{
  const float* obsv = (const float*)d_in[0];
  const float* noise = (const float*)d_in[1];
  const float* Wemb = (const float*)d_in[2];
  const float* bemb = (const float*)d_in[3];
  const float* Wih = (const float*)d_in[4];
  const float* Whh = (const float*)d_in[5];
  const float* bih = (const float*)d_in[6];
  const float* bhh = (const float*)d_in[7];
  const float* Wf1 = (const float*)d_in[8];
  const float* bf1 = (const float*)d_in[9];
  const float* Wf2 = (const float*)d_in[10];
  const float* bf2 = (const float*)d_in[11];
  const float* Wf3 = (const float*)d_in[12];
  const float* bf3 = (const float*)d_in[13];
  const float* Wa = (const float*)d_in[14];
  const float* ba = (const float*)d_in[15];
  const float* Wd1 = (const float*)d_in[16];
  const float* bd1 = (const float*)d_in[17];
  const float* Wd2 = (const float*)d_in[18];
  const float* bd2 = (const float*)d_in[19];
  const float* Wd3 = (const float*)d_in[20];
  const float* bd3 = (const float*)d_in[21];
  const float* Wd4 = (const float*)d_in[22];
  const float* bd4 = (const float*)d_in[23];
  float* ws = (float*)d_ws;
  float* out = (float*)d_out;

  k_tr<<<200, 256, 0, stream>>>(Wih, Whh, Wd1, Wd2, Wd3, Wa, ws);
  k_enc<<<48, 512, 0, stream>>>(obsv, Wemb, bemb, bih, bhh, ws);
  k_social<<<768, 128, 0, stream>>>(ba, Wf3, bf3, ws);
  k_attn<<<768, 64, 0, stream>>>(obsv, Wf1, bf1, Wf2, bf2, ws);
  k_dec<<<48, 512, 0, stream>>>(obsv, noise, Wemb, bemb, bd1, bd2, bd3, bd4, Wd4,
                                bih, bhh, ws, out);
}